// Round 1
// baseline (156.717 us; speedup 1.0000x reference)
//
#include <hip/hip_runtime.h>
#include <cstdint>
#include <cstddef>

#define B_SZ 4096
#define C_SZ 1000
#define V_SZ 8000
#define RW 128              // padded row stride in u64 (125 used)
#define THRESHF 0.8f
#define SCALEF 0.1f

#define OFF_CI 0
#define OFF_CS (B_SZ * 5)
#define OFF_HI (2 * B_SZ * 5)
#define OFF_HS (3 * B_SZ * 5)
#define OFF_C1 (3 * B_SZ * 5 + B_SZ)
#define OFF_C2 (3 * B_SZ * 5 + 2 * B_SZ)

// ---------------- pack matrix rows into bitmasks ----------------
__global__ __launch_bounds__(256) void pack_kernel(const int* __restrict__ mat,
                                                   unsigned long long* __restrict__ packed) {
  const int c = blockIdx.x;
  const int tid = threadIdx.x;
  const int lane = tid & 63;
  const int wv = tid >> 6;
  const int* row = mat + (size_t)c * V_SZ;
  for (int base = 0; base < 8192; base += 256) {
    const int k = base + tid;
    int v = 0;
    if (k < V_SZ) v = row[k];
    unsigned long long msk = __ballot(v != 0);
    if (lane == 0) packed[(size_t)c * RW + ((base >> 6) + wv)] = msk;
  }
}

// ---------------- class softmax + top5 ----------------
__global__ __launch_bounds__(256) void class_topk_kernel(const float* __restrict__ logits,
                                                         float* __restrict__ out) {
  const int b = blockIdx.x;
  const int tid = threadIdx.x;
  const int lane = tid & 63;
  const int wv = tid >> 6;
  const float* row = logits + (size_t)b * V_SZ;
  float v[32];
#pragma unroll
  for (int q = 0; q < 32; ++q) {
    int k = tid + (q << 8);
    v[q] = (k < V_SZ) ? row[k] : -INFINITY;
  }
  __shared__ float sred[4];
  __shared__ int sredi[4];
  // max
  float lm = -INFINITY;
#pragma unroll
  for (int q = 0; q < 32; ++q) lm = fmaxf(lm, v[q]);
#pragma unroll
  for (int o = 32; o >= 1; o >>= 1) lm = fmaxf(lm, __shfl_xor(lm, o));
  if (lane == 0) sred[wv] = lm;
  __syncthreads();
  const float m = fmaxf(fmaxf(sred[0], sred[1]), fmaxf(sred[2], sred[3]));
  // sum of exp
  float ls = 0.f;
#pragma unroll
  for (int q = 0; q < 32; ++q) ls += expf(v[q] - m);
#pragma unroll
  for (int o = 32; o >= 1; o >>= 1) ls += __shfl_xor(ls, o);
  __syncthreads();
  if (lane == 0) sred[wv] = ls;
  __syncthreads();
  const float ssum = sred[0] + sred[1] + sred[2] + sred[3];
  // iterative top-5 on raw logits (same order as probs)
  for (int r = 0; r < 5; ++r) {
    float bv = -INFINITY;
    int bi = 0;
#pragma unroll
    for (int q = 0; q < 32; ++q) {
      if (v[q] > bv) { bv = v[q]; bi = tid + (q << 8); }
    }
#pragma unroll
    for (int o = 32; o >= 1; o >>= 1) {
      float ov = __shfl_xor(bv, o);
      int oi = __shfl_xor(bi, o);
      if (ov > bv || (ov == bv && oi < bi)) { bv = ov; bi = oi; }
    }
    __syncthreads();
    if (lane == 0) { sred[wv] = bv; sredi[wv] = bi; }
    __syncthreads();
    bv = sred[0]; bi = sredi[0];
#pragma unroll
    for (int w = 1; w < 4; ++w) {
      if (sred[w] > bv || (sred[w] == bv && sredi[w] < bi)) { bv = sred[w]; bi = sredi[w]; }
    }
    if ((bi & 255) == tid) {
      const int sl = bi >> 8;
#pragma unroll
      for (int q = 0; q < 32; ++q)
        if (q == sl) v[q] = -INFINITY;
    }
    if (tid == 0) {
      out[OFF_CI + b * 5 + r] = (float)bi;
      out[OFF_CS + b * 5 + r] = expf(bv - m) / ssum;
    }
  }
}

// ---------------- per-sample component decode ----------------
__global__ __launch_bounds__(256) void decode_kernel(const float* __restrict__ compo_logits,
                                                     const float* __restrict__ co_occ,
                                                     const unsigned long long* __restrict__ packed,
                                                     float* __restrict__ out) {
  const int b = blockIdx.x;
  const int tid = threadIdx.x;
  const int lane = tid & 63;
  const int wv = tid >> 6;
  __shared__ float s_m[C_SZ];    // sel ? score : 0   (for adj)
  __shared__ float s_sc[1024];   // scores (mutated during extraction)
  __shared__ short s_list[C_SZ];
  __shared__ int s_nsel;
  __shared__ float red_v[4];
  __shared__ int red_i[4];
  __shared__ int red_n[4];

  const float* lg = compo_logits + (size_t)b * C_SZ;
  for (int k = tid; k < 1024; k += 256) {
    if (k < C_SZ) {
      float x = lg[k];
      float s = 1.0f / (1.0f + expf(-x));
      s_sc[k] = s;
      s_m[k] = (s > THRESHF) ? s : 0.0f;
    } else {
      s_sc[k] = -INFINITY;
    }
  }
  __syncthreads();
  // compact selected indices (ascending) — wave 0
  if (wv == 0) {
    int off = 0;
    for (int base = 0; base < C_SZ; base += 64) {
      const int k = base + lane;
      float mv = (k < C_SZ) ? s_m[k] : 0.0f;
      unsigned long long msk = __ballot(mv != 0.0f);
      int rank = __popcll(msk & ((1ull << lane) - 1ull));
      if (mv != 0.0f) s_list[off + rank] = (short)k;
      off += __popcll(msk);
    }
    if (lane == 0) s_nsel = off;
  }
  __syncthreads();
  const int nadj = s_nsel;
  // adj[j] accumulation: j = tid, tid+256, tid+512, tid+768
  float a0 = 0.f, a1 = 0.f, a2 = 0.f, a3 = 0.f;
  for (int e = 0; e < nadj; ++e) {
    const int i = s_list[e];
    const float mm = s_m[i];
    const float* rp = co_occ + (size_t)i * C_SZ;
    a0 += mm * rp[tid];
    a1 += mm * rp[tid + 256];
    a2 += mm * rp[tid + 512];
    if (tid < C_SZ - 768) a3 += mm * rp[tid + 768];
  }
  // final scores, block argmax (ties -> lowest idx), count(>THRESH)
  float bv = -INFINITY;
  int bi = 0;
  int cnt = 0;
  {
    float sc;
    sc = s_sc[tid] + SCALEF * a0;
    s_sc[tid] = sc;
    if (sc > THRESHF) cnt++;
    if (sc > bv) { bv = sc; bi = tid; }
    sc = s_sc[tid + 256] + SCALEF * a1;
    s_sc[tid + 256] = sc;
    if (sc > THRESHF) cnt++;
    if (sc > bv) { bv = sc; bi = tid + 256; }
    sc = s_sc[tid + 512] + SCALEF * a2;
    s_sc[tid + 512] = sc;
    if (sc > THRESHF) cnt++;
    if (sc > bv) { bv = sc; bi = tid + 512; }
    if (tid < C_SZ - 768) {
      sc = s_sc[tid + 768] + SCALEF * a3;
      s_sc[tid + 768] = sc;
      if (sc > THRESHF) cnt++;
      if (sc > bv) { bv = sc; bi = tid + 768; }
    }
  }
#pragma unroll
  for (int o = 32; o >= 1; o >>= 1) {
    float ov = __shfl_xor(bv, o);
    int oi = __shfl_xor(bi, o);
    cnt += __shfl_xor(cnt, o);
    if (ov > bv || (ov == bv && oi < bi)) { bv = ov; bi = oi; }
  }
  if (lane == 0) { red_v[wv] = bv; red_i[wv] = bi; red_n[wv] = cnt; }
  __syncthreads();
  float mxv = red_v[0];
  int mxi = red_i[0];
  const int nsel = red_n[0] + red_n[1] + red_n[2] + red_n[3];
#pragma unroll
  for (int w = 1; w < 4; ++w) {
    if (red_v[w] > mxv || (red_v[w] == mxv && red_i[w] < mxi)) { mxv = red_v[w]; mxi = red_i[w]; }
  }
  if (tid == 0) s_sc[mxi] = -INFINITY;
  __syncthreads();
  if (wv != 0) return;  // rest is wave 0 only (no __syncthreads below)

  // scores into registers: slot q holds index lane + 64q
  float p[16];
#pragma unroll
  for (int q = 0; q < 16; ++q) {
    const int k = lane + (q << 6);
    p[q] = (k < C_SZ) ? s_sc[k] : -INFINITY;
  }
  const unsigned long long* pr = packed + (size_t)mxi * RW;
  unsigned long long h0 = pr[lane];
  unsigned long long h1 = pr[64 + lane];  // words 125..127 are zero-padded
  int pc = __popcll(h0) + __popcll(h1);
#pragma unroll
  for (int o = 32; o >= 1; o >>= 1) pc += __shfl_xor(pc, o);
  int i = 1;
  float last_v = mxv;
  unsigned long long ph0 = h0, ph1 = h1;
  int ppc = pc;
  float plast = mxv;
  while (i < nsel && pc > 1) {
    // extract next max (ties -> lowest idx)
    float ev = -INFINITY;
    int ei = 0;
#pragma unroll
    for (int q = 0; q < 16; ++q) {
      if (p[q] > ev) { ev = p[q]; ei = lane + (q << 6); }
    }
#pragma unroll
    for (int o = 32; o >= 1; o >>= 1) {
      float ov = __shfl_xor(ev, o);
      int oi = __shfl_xor(ei, o);
      if (ov > ev || (ov == ev && oi < ei)) { ev = ov; ei = oi; }
    }
    if ((ei & 63) == lane) {
      const int sl = ei >> 6;
#pragma unroll
      for (int q = 0; q < 16; ++q)
        if (q == sl) p[q] = -INFINITY;
    }
    const unsigned long long* r2 = packed + (size_t)ei * RW;
    ph0 = h0; ph1 = h1; ppc = pc; plast = last_v;
    h0 &= r2[lane];
    h1 &= r2[64 + lane];
    pc = __popcll(h0) + __popcll(h1);
#pragma unroll
    for (int o = 32; o >= 1; o >>= 1) pc += __shfl_xor(pc, o);
    last_v = ev;
    ++i;
  }
  if (pc == 0) {  // rollback
    h0 = ph0; h1 = ph1; pc = ppc; last_v = plast;
  }
  const float hit_score = last_v;

  // rank prefix over 125 words, emit first 5 set bits
  const int c0 = __popcll(h0), c1 = __popcll(h1);
  int s0 = c0;
#pragma unroll
  for (int o = 1; o < 64; o <<= 1) {
    int n = __shfl_up(s0, o);
    if (lane >= o) s0 += n;
  }
  const int tot0 = __shfl(s0, 63);
  const int pre0 = s0 - c0;
  int s1 = c1;
#pragma unroll
  for (int o = 1; o < 64; o <<= 1) {
    int n = __shfl_up(s1, o);
    if (lane >= o) s1 += n;
  }
  const int tot = tot0 + __shfl(s1, 63);
  const int pre1 = tot0 + s1 - c1;
  {
    unsigned long long x = h0;
    int r = pre0;
    while (x && r < 5) {
      int bp = __ffsll((unsigned long long)x) - 1;
      out[OFF_HI + b * 5 + r] = (float)((lane << 6) + bp);
      x &= x - 1;
      ++r;
    }
    x = h1;
    r = pre1;
    while (x && r < 5) {
      int bp = __ffsll((unsigned long long)x) - 1;
      out[OFF_HI + b * 5 + r] = (float)(((64 + lane) << 6) + bp);
      x &= x - 1;
      ++r;
    }
  }
  // first hit bit index (for combined outputs)
  int fb = 0x7fffffff;
  if (c0) fb = (lane << 6) + __ffsll((unsigned long long)h0) - 1;
  else if (c1) fb = ((64 + lane) << 6) + __ffsll((unsigned long long)h1) - 1;
#pragma unroll
  for (int o = 32; o >= 1; o >>= 1) fb = min(fb, __shfl_xor(fb, o));
  if (lane == 0) {
    const int num_hit = tot < 5 ? tot : 5;
    for (int r = num_hit; r < 5; ++r) out[OFF_HI + b * 5 + r] = -1.0f;
    out[OFF_HS + b] = hit_score;
    const float ci0 = out[OFF_CI + b * 5];
    const float cs0 = out[OFF_CS + b * 5];
    out[OFF_C1 + b] = (num_hit == 1) ? (float)fb : ci0;
    out[OFF_C2 + b] = (cs0 < 0.85f && num_hit == 1) ? (float)fb : ci0;
  }
}

extern "C" void kernel_launch(void* const* d_in, const int* in_sizes, int n_in,
                              void* d_out, int out_size, void* d_ws, size_t ws_size,
                              hipStream_t stream) {
  (void)in_sizes; (void)n_in; (void)out_size; (void)ws_size;
  const float* class_logits = (const float*)d_in[0];
  const float* compo_logits = (const float*)d_in[1];
  const float* co_occ = (const float*)d_in[2];
  const int* mat = (const int*)d_in[3];
  float* out = (float*)d_out;
  unsigned long long* packed = (unsigned long long*)d_ws;  // 1000 * 128 * 8 B = 1 MB

  pack_kernel<<<C_SZ, 256, 0, stream>>>(mat, packed);
  class_topk_kernel<<<B_SZ, 256, 0, stream>>>(class_logits, out);
  decode_kernel<<<B_SZ, 256, 0, stream>>>(compo_logits, co_occ, packed, out);
}